// Round 12
// baseline (293.512 us; speedup 1.0000x reference)
//
#include <hip/hip_runtime.h>
#include <hip/hip_bf16.h>

// Problem constants (shapes fixed by the reference)
#define XS   2
#define NP   96
#define NLAY 3
#define NXI  (XS*NP)   // 192
// L_INPUT = 3, DIMS = (1,3,5,7), MAX_DIM = 7, NUM_CG = 4, NUM_CH = 16

// packed (rep,dim) index tables: 16 = 1+3+5+7 entries
__constant__ int P2R_c[16] = {0, 1,1,1, 2,2,2,2,2, 3,3,3,3,3,3,3};
__constant__ int P2D_c[16] = {0, 0,1,2, 0,1,2,3,4, 0,1,2,3,4,5,6};
__constant__ int DIMS_c[4] = {1,3,5,7};
__constant__ int OFF_c[4]  = {0,1,4,9};

__device__ inline float2 cmadd(float2 acc, float2 a, float2 b){
    acc.x += a.x*b.x - a.y*b.y;
    acc.y += a.x*b.y + a.y*b.x;
    return acc;
}

// One prep kernel, three flat ranges:
//  [0, 2352)            cgf[k][qr][s][t] = sum_g cg[g,3,s,3,t,q,r]*f[k,q,g]
//  [2352, 2352+16384)   PK2[ls][mt][qr][g] = cg[g,l,s,m,t,q,r]
//  [18736, 18736+49152) pack V -> Vp[x][j][mt16][c16]
#define PREP_TOTAL (2352 + 16384 + 49152)
__global__ void prep_kernel(const float* __restrict__ cg,
                            const float* __restrict__ f,
                            const float* __restrict__ Vin,
                            float* __restrict__ cgf,
                            float* __restrict__ PK2,
                            float* __restrict__ Vp){
    int idx = blockIdx.x*256 + threadIdx.x;
    if (idx < 2352){
        int k  = idx / (16*49);
        int rem = idx % (16*49);
        int qr = rem / 49;
        int st = rem % 49;
        int s = st / 7, t = st % 7;
        int q = P2R_c[qr], r = P2D_c[qr];
        float2 acc = make_float2(0.f, 0.f);
        for (int g = 0; g < 4; ++g){
            const float* cgp = cg + (((((((size_t)g*4+3)*7 + s)*4 + 3)*7 + t)*4 + q)*7 + r)*2;
            const float* fp  = f + ((k*4 + q)*4 + g)*2;
            acc = cmadd(acc, make_float2(cgp[0], cgp[1]), make_float2(fp[0], fp[1]));
        }
        cgf[idx*2]   = acc.x;
        cgf[idx*2+1] = acc.y;
    } else if (idx < 2352 + 16384){
        int id = idx - 2352;           // = ((ls*16+mt)*16+qr)*4+g
        int g  = id & 3;
        int qr = (id >> 2) & 15;
        int mt = (id >> 6) & 15;
        int ls = (id >> 10) & 15;
        int l = P2R_c[ls], s = P2D_c[ls];
        int m = P2R_c[mt], t = P2D_c[mt];
        int q = P2R_c[qr], r = P2D_c[qr];
        size_t co = (((((((size_t)g*4 + l)*7 + s)*4 + m)*7 + t)*4 + q)*7 + r);
        PK2[id*2]   = cg[co*2];
        PK2[id*2+1] = cg[co*2+1];
    } else if (idx < PREP_TOTAL){
        int id = idx - 18736;          // = (xj*16+mt)*16+c
        int c  = id & 15;
        int mt = (id >> 4) & 15;
        int xj = id >> 8;
        int m = P2R_c[mt], t = P2D_c[mt];
        const float* p = Vin + ((((size_t)xj*4 + m)*16 + c)*7 + t)*2;
        Vp[id*2]   = p[0];
        Vp[id*2+1] = p[1];
    }
}

// filt_all_kernel: grid 3*192 + 12 zero-blocks, 256 threads.
#define ZBLK 12
__global__ __launch_bounds__(256)
void filt_all_kernel(const float* __restrict__ X,
                     const float* __restrict__ cgf,     // [k][16][49] complex
                     float* __restrict__ filt_g,        // [k][xi][96][16] complex
                     float* __restrict__ zbase)         // VB (3 buffers contiguous)
{
    if (blockIdx.x >= NLAY*NXI){
        const int zb = blockIdx.x - NLAY*NXI;
        float4* dst = (float4*)zbase;
        const int base = (zb*256 + (int)threadIdx.x)*24;
        const float4 z4 = make_float4(0.f,0.f,0.f,0.f);
        #pragma unroll
        for (int u = 0; u < 24; ++u) dst[base + u] = z4;
        return;
    }

    __shared__ float2 cgf_s[784];      // 6272 B
    __shared__ float2 dX_s[NP][7];     // 5376 B

    const int tid = threadIdx.x;
    const int k  = blockIdx.x / NXI;
    const int xi = blockIdx.x % NXI;
    const int x = xi / NP, i = xi % NP;

    const float2* cgf_k = (const float2*)cgf + (size_t)k*784;
    for (int u = tid; u < 784; u += 256) cgf_s[u] = cgf_k[u];
    for (int e = tid; e < NP*7; e += 256){
        int j = e / 7, s = e % 7;
        const float* Xj = X + (((size_t)x*NP + j)*7 + s)*2;
        const float* Xi = X + (((size_t)x*NP + i)*7 + s)*2;
        dX_s[j][s] = make_float2(Xj[0]-Xi[0], Xj[1]-Xi[1]);
    }
    __syncthreads();

    float2* out = (float2*)filt_g + (size_t)blockIdx.x*NP*16;
    for (int e = tid; e < NP*16; e += 256){
        int j = e >> 4, qr = e & 15;
        const float2* cb = cgf_s + qr*49;
        float2 acc = make_float2(0.f, 0.f);
        #pragma unroll
        for (int s = 0; s < 7; ++s){
            float2 inner = make_float2(0.f, 0.f);
            #pragma unroll
            for (int t = 0; t < 7; ++t)
                inner = cmadd(inner, cb[s*7 + t], dX_s[j][t]);
            acc = cmadd(acc, dX_s[j][s], inner);
        }
        if (qr >= 9){ float2 dv = dX_s[j][qr-9]; acc.x += dv.x; acc.y += dv.y; }
        out[e] = acc;
    }
}

// TS_kernel: grid 768 = cq*192 + xi (xi fastest -> XCD-local), 256 threads.
// Reduction-free thread assignments: 3 barriers per block total.
//  T: thread (ls, colq) owns 1x4 tile, full 96-j loop (no jg reduction).
//  S: thread (cl, qr, g) owns one accumulator, full 256-lsmt loop; PK read
//     direct from global, lane = qr*4+g -> one 512B contiguous segment/wave,
//     identical across waves (L1-served). No PK staging, no chunk barriers.
//  W: small LDS pass + atomic accumulate (Vout pre-zeroed).
__global__ __launch_bounds__(256)
void TS_kernel(const float* __restrict__ filt_gk,  // [xi][96][16] complex
               const float* __restrict__ PK2,      // [ls][mt][qr][g] complex
               const float* __restrict__ W_k,      // [q][c][g][d] complex
               const float* __restrict__ Vin,      // packed [x][j][mtc]
               float* __restrict__ Vout)           // packed [xi][qr*16+d], pre-zeroed
{
    __shared__ __align__(16) float2 filt_s[NP][16];  // 12288 B
    __shared__ __align__(16) float2 T_s[16][66];     // 8448 B (16 mt x 4 cl + pad 2)
    __shared__ __align__(16) float2 S_s[256];        // 2048 B  [cl][qr][g]

    const int tid = threadIdx.x;
    const int xi = blockIdx.x % NXI;   // xi fastest -> XCD-local
    const int cq = blockIdx.x / NXI;
    const int x  = xi / NP;

    // stage filters for this xi (24 KB, same-XCD L2 hit)
    {
        const float2* src = (const float2*)filt_gk + (size_t)xi*NP*16;
        float2* dst = &filt_s[0][0];
        for (int e = tid; e < NP*16; e += 256) dst[e] = src[e];
    }
    __syncthreads();

    // ---- phase T: T[ls][colq*4+u] = sum_j filt[j][ls] * V[j][colq*16+cq*4+u]
    {
        const int ls   = tid >> 4;
        const int colq = tid & 15;
        const float4* V4 = (const float4*)((const float2*)Vin + (size_t)x*NP*256);
        const int vcol = colq*8 + cq*2;   // float4 units within the 128-f4 j-row
        float2 acc0 = make_float2(0.f,0.f), acc1 = acc0, acc2 = acc0, acc3 = acc0;
        #pragma unroll 4
        for (int j = 0; j < NP; ++j){
            float2 fv = filt_s[j][ls];
            float4 va = V4[j*128 + vcol];
            float4 vb = V4[j*128 + vcol + 1];
            acc0 = cmadd(acc0, fv, make_float2(va.x, va.y));
            acc1 = cmadd(acc1, fv, make_float2(va.z, va.w));
            acc2 = cmadd(acc2, fv, make_float2(vb.x, vb.y));
            acc3 = cmadd(acc3, fv, make_float2(vb.z, vb.w));
        }
        float4* Trow = (float4*)&T_s[ls][0];      // 33 float4 per row
        Trow[colq*2]   = make_float4(acc0.x, acc0.y, acc1.x, acc1.y);
        Trow[colq*2+1] = make_float4(acc2.x, acc2.y, acc3.x, acc3.y);
    }
    __syncthreads();

    // ---- phase S: S[cl][qr][g] = sum_{lm} PK[lm][qr][g] * T[lm>>4][(lm&15)*4+cl]
    {
        const int cl = tid >> 6;           // wave index
        const int qg = tid & 63;           // qr*4+g lane
        const float2* PKp = (const float2*)PK2 + qg;
        float2 sacc = make_float2(0.f, 0.f);
        #pragma unroll 8
        for (int lm = 0; lm < 256; ++lm){
            float2 pk = PKp[(size_t)lm*64];
            float2 tv = T_s[lm >> 4][(lm & 15)*4 + cl];
            sacc = cmadd(sacc, pk, tv);
        }
        S_s[cl*64 + qg] = sacc;
    }
    __syncthreads();

    // ---- phase W (partial over this cq): Vout[qr][d] += sum_{cl,g} S*W
    {
        const int qr2 = tid >> 4, d = tid & 15;
        const int q = P2R_c[qr2];
        float2 acc = make_float2(0.f, 0.f);
        const float2* Wb = (const float2*)W_k + (size_t)q*16*4*16 + d;
        #pragma unroll
        for (int cl2 = 0; cl2 < 4; ++cl2){
            const int c = cq*4 + cl2;
            #pragma unroll
            for (int g2 = 0; g2 < 4; ++g2){
                float2 sv = S_s[cl2*64 + qr2*4 + g2];
                float2 wv = Wb[(c*4 + g2)*16];
                acc = cmadd(acc, sv, wv);
            }
        }
        float* outp = (float*)Vout + ((size_t)xi*256 + tid)*2;
        atomicAdd(outp,     acc.x);
        atomicAdd(outp + 1, acc.y);
    }
}

// unpack final packed V -> d_out (x,i,q,d,r,z), zeros at r >= DIMS[q]
__global__ void unpack_V_kernel(const float* __restrict__ Vp,
                                float* __restrict__ out){
    int idx = blockIdx.x*blockDim.x + threadIdx.x;
    if (idx >= XS*NP*4*16*7) return;
    int r  = idx % 7;
    int d  = (idx / 7) % 16;
    int q  = (idx / (7*16)) % 4;
    int xi = idx / (7*16*4);
    float2 v = make_float2(0.f, 0.f);
    if (r < DIMS_c[q]){
        v = ((const float2*)Vp)[(size_t)xi*256 + (OFF_c[q] + r)*16 + d];
    }
    ((float2*)out)[idx] = v;
}

extern "C" void kernel_launch(void* const* d_in, const int* in_sizes, int n_in,
                              void* d_out, int out_size, void* d_ws, size_t ws_size,
                              hipStream_t stream) {
    const float* X  = (const float*)d_in[0];
    // d_in[1] is 'l' (always 3, hardcoded)
    const float* V  = (const float*)d_in[2];
    const float* cg = (const float*)d_in[3];
    const float* f  = (const float*)d_in[4];
    const float* W  = (const float*)d_in[5];
    // d_in[6] is C4 (plain complex product, hardcoded)

    // ws layout (floats)
    float* ws     = (float*)d_ws;
    float* cgf    = ws;                         // 3*784*2   = 4704
    float* PK2    = cgf   + 4704;               // 16384*2   = 32768
    float* VA     = PK2   + 32768;              // 192*256*2 = 98304
    float* VB     = VA + 98304;                 // 98304
    float* VC     = VB + 98304;                 // 98304
    float* VD     = VC + 98304;                 // 98304
    float* filt_g = VD + 98304;                 // 3*192*96*16*2 = 1769472

    prep_kernel<<<(PREP_TOTAL + 255)/256, 256, 0, stream>>>(cg, f, V, cgf, PK2, VA);
    // filters for all layers + zero VB/VC/VD (contiguous)
    filt_all_kernel<<<NLAY*NXI + ZBLK, 256, 0, stream>>>(X, cgf, filt_g, VB);

    const float* W0 = W;
    const float* W1 = W + (size_t)1*4*16*4*16*2;
    const float* W2 = W + (size_t)2*4*16*4*16*2;
    const float* f0 = filt_g;
    const float* f1 = filt_g + (size_t)1*NXI*NP*16*2;
    const float* f2 = filt_g + (size_t)2*NXI*NP*16*2;

    TS_kernel<<<NXI*4, 256, 0, stream>>>(f0, PK2, W0, VA, VB);
    TS_kernel<<<NXI*4, 256, 0, stream>>>(f1, PK2, W1, VB, VC);
    TS_kernel<<<NXI*4, 256, 0, stream>>>(f2, PK2, W2, VC, VD);

    unpack_V_kernel<<<(XS*NP*4*16*7 + 255)/256, 256, 0, stream>>>(VD, (float*)d_out);
}

// Round 13
// 134.045 us; speedup vs baseline: 2.1897x; 2.1897x over previous
//
#include <hip/hip_runtime.h>
#include <hip/hip_bf16.h>

// Problem constants (shapes fixed by the reference)
#define XS   2
#define NP   96
#define NLAY 3
#define NXI  (XS*NP)   // 192
// L_INPUT = 3, DIMS = (1,3,5,7), MAX_DIM = 7, NUM_CG = 4, NUM_CH = 16

// packed (rep,dim) index tables: 16 = 1+3+5+7 entries
__constant__ int P2R_c[16] = {0, 1,1,1, 2,2,2,2,2, 3,3,3,3,3,3,3};
__constant__ int P2D_c[16] = {0, 0,1,2, 0,1,2,3,4, 0,1,2,3,4,5,6};
__constant__ int DIMS_c[4] = {1,3,5,7};
__constant__ int OFF_c[4]  = {0,1,4,9};

__device__ inline float2 cmadd(float2 acc, float2 a, float2 b){
    acc.x += a.x*b.x - a.y*b.y;
    acc.y += a.x*b.y + a.y*b.x;
    return acc;
}

// One prep kernel, three flat ranges:
//  [0, 2352)            cgf[k][qr][s][t] = sum_g cg[g,3,s,3,t,q,r]*f[k,q,g]
//  [2352, 2352+16384)   PK2[ls][mt][qr][g] = cg[g,l,s,m,t,q,r]
//  [18736, 18736+49152) pack V -> Vp[x][j][mt16][c16]
#define PREP_TOTAL (2352 + 16384 + 49152)
__global__ void prep_kernel(const float* __restrict__ cg,
                            const float* __restrict__ f,
                            const float* __restrict__ Vin,
                            float* __restrict__ cgf,
                            float* __restrict__ PK2,
                            float* __restrict__ Vp){
    int idx = blockIdx.x*256 + threadIdx.x;
    if (idx < 2352){
        int k  = idx / (16*49);
        int rem = idx % (16*49);
        int qr = rem / 49;
        int st = rem % 49;
        int s = st / 7, t = st % 7;
        int q = P2R_c[qr], r = P2D_c[qr];
        float2 acc = make_float2(0.f, 0.f);
        for (int g = 0; g < 4; ++g){
            const float* cgp = cg + (((((((size_t)g*4+3)*7 + s)*4 + 3)*7 + t)*4 + q)*7 + r)*2;
            const float* fp  = f + ((k*4 + q)*4 + g)*2;
            acc = cmadd(acc, make_float2(cgp[0], cgp[1]), make_float2(fp[0], fp[1]));
        }
        cgf[idx*2]   = acc.x;
        cgf[idx*2+1] = acc.y;
    } else if (idx < 2352 + 16384){
        int id = idx - 2352;           // = ((ls*16+mt)*16+qr)*4+g
        int g  = id & 3;
        int qr = (id >> 2) & 15;
        int mt = (id >> 6) & 15;
        int ls = (id >> 10) & 15;
        int l = P2R_c[ls], s = P2D_c[ls];
        int m = P2R_c[mt], t = P2D_c[mt];
        int q = P2R_c[qr], r = P2D_c[qr];
        size_t co = (((((((size_t)g*4 + l)*7 + s)*4 + m)*7 + t)*4 + q)*7 + r);
        PK2[id*2]   = cg[co*2];
        PK2[id*2+1] = cg[co*2+1];
    } else if (idx < PREP_TOTAL){
        int id = idx - 18736;          // = (xj*16+mt)*16+c
        int c  = id & 15;
        int mt = (id >> 4) & 15;
        int xj = id >> 8;
        int m = P2R_c[mt], t = P2D_c[mt];
        const float* p = Vin + ((((size_t)xj*4 + m)*16 + c)*7 + t)*2;
        Vp[id*2]   = p[0];
        Vp[id*2+1] = p[1];
    }
}

// filt_all_kernel: grid 3*192 + 12 zero-blocks, 256 threads.
#define ZBLK 12
__global__ __launch_bounds__(256)
void filt_all_kernel(const float* __restrict__ X,
                     const float* __restrict__ cgf,     // [k][16][49] complex
                     float* __restrict__ filt_g,        // [k][xi][96][16] complex
                     float* __restrict__ zbase)         // VB (3 buffers contiguous)
{
    if (blockIdx.x >= NLAY*NXI){
        const int zb = blockIdx.x - NLAY*NXI;
        float4* dst = (float4*)zbase;
        const int base = (zb*256 + (int)threadIdx.x)*24;
        const float4 z4 = make_float4(0.f,0.f,0.f,0.f);
        #pragma unroll
        for (int u = 0; u < 24; ++u) dst[base + u] = z4;
        return;
    }

    __shared__ float2 cgf_s[784];      // 6272 B
    __shared__ float2 dX_s[NP][7];     // 5376 B

    const int tid = threadIdx.x;
    const int k  = blockIdx.x / NXI;
    const int xi = blockIdx.x % NXI;
    const int x = xi / NP, i = xi % NP;

    const float2* cgf_k = (const float2*)cgf + (size_t)k*784;
    for (int u = tid; u < 784; u += 256) cgf_s[u] = cgf_k[u];
    for (int e = tid; e < NP*7; e += 256){
        int j = e / 7, s = e % 7;
        const float* Xj = X + (((size_t)x*NP + j)*7 + s)*2;
        const float* Xi = X + (((size_t)x*NP + i)*7 + s)*2;
        dX_s[j][s] = make_float2(Xj[0]-Xi[0], Xj[1]-Xi[1]);
    }
    __syncthreads();

    float2* out = (float2*)filt_g + (size_t)blockIdx.x*NP*16;
    for (int e = tid; e < NP*16; e += 256){
        int j = e >> 4, qr = e & 15;
        const float2* cb = cgf_s + qr*49;
        float2 acc = make_float2(0.f, 0.f);
        #pragma unroll
        for (int s = 0; s < 7; ++s){
            float2 inner = make_float2(0.f, 0.f);
            #pragma unroll
            for (int t = 0; t < 7; ++t)
                inner = cmadd(inner, cb[s*7 + t], dX_s[j][t]);
            acc = cmadd(acc, dX_s[j][s], inner);
        }
        if (qr >= 9){ float2 dv = dX_s[j][qr-9]; acc.x += dv.x; acc.y += dv.y; }
        out[e] = acc;
    }
}

// TS_kernel: grid 768 = cq*192 + xi (xi fastest -> XCD-local), 256 threads.
// T: round-9 proven structure (24j, 4x4 reg tile, 4-stage jg reduce).
// S: thread (lsq=wave, qg=lane); each wave reads a DISTINCT quarter of PK
//    directly from global (512B coalesced wave-loads; PK read once per block,
//    no LDS staging, no chunk barriers); sacc[4] covers the 4 local channels
//    via T_s wave-broadcast reads; 4-stage lsq reduce into S_s[cl][qg].
// W: LDS pass + atomic accumulate (Vout pre-zeroed).
// Barriers/block: 9 (was 22). LDS 23 KB (was 37).
__global__ __launch_bounds__(256)
void TS_kernel(const float* __restrict__ filt_gk,  // [xi][96][16] complex
               const float* __restrict__ PK2,      // [ls][mt][qr][g] complex
               const float* __restrict__ W_k,      // [q][c][g][d] complex
               const float* __restrict__ Vin,      // packed [x][j][mtc]
               float* __restrict__ Vout)           // packed [xi][qr*16+d], pre-zeroed
{
    __shared__ __align__(16) float2 filt_s[NP][16];  // 12288 B
    __shared__ __align__(16) float2 T_s[16][66];     // 8448 B (rows padded +2)
    __shared__ __align__(16) float2 S_s[256];        // 2048 B  [cl][qg]

    const int tid = threadIdx.x;
    const int xi = blockIdx.x % NXI;   // xi fastest -> XCD-local
    const int cq = blockIdx.x / NXI;
    const int x  = xi / NP;

    // stage filters for this xi (24 KB, same-XCD L2 hit)
    {
        const float2* src = (const float2*)filt_gk + (size_t)xi*NP*16;
        float2* dst = &filt_s[0][0];
        for (int e = tid; e < NP*16; e += 256) dst[e] = src[e];
    }
    __syncthreads();

    // ---- phase T: T[ls][col] = sum_j filt[j][ls]*V[j][mtc], 4x4 reg tile,
    // 4-way j-split. col = mt*4+cl (local), mtc = mt*16 + cq*4 + cl (global).
    const int jg   = tid >> 6;         // 0..3
    const int pos  = tid & 63;
    const int lsq  = pos >> 4;         // ls quad
    const int colq = pos & 15;         // = mt
    {
        const float4* F4 = (const float4*)&filt_s[0][0];  // j row = 8 float4
        const float4* V4 = (const float4*)((const float2*)Vin + (size_t)x*NP*256);
        float2 acc[4][4];
        #pragma unroll
        for (int u = 0; u < 4; ++u)
            #pragma unroll
            for (int v = 0; v < 4; ++v) acc[u][v] = make_float2(0.f, 0.f);
        const int j0 = jg*24;
        const int vcol = colq*8 + cq*2;    // float4 units within 128-f4 row
        #pragma unroll 2
        for (int jj = 0; jj < 24; ++jj){
            const int j = j0 + jj;
            float4 fa = F4[j*8 + lsq*2];
            float4 fb = F4[j*8 + lsq*2 + 1];
            float4 va = V4[j*128 + vcol];
            float4 vb = V4[j*128 + vcol + 1];
            float2 f0 = make_float2(fa.x, fa.y), f1 = make_float2(fa.z, fa.w);
            float2 f2 = make_float2(fb.x, fb.y), f3 = make_float2(fb.z, fb.w);
            float2 v0 = make_float2(va.x, va.y), v1 = make_float2(va.z, va.w);
            float2 v2 = make_float2(vb.x, vb.y), v3 = make_float2(vb.z, vb.w);
            acc[0][0]=cmadd(acc[0][0],f0,v0); acc[0][1]=cmadd(acc[0][1],f0,v1);
            acc[0][2]=cmadd(acc[0][2],f0,v2); acc[0][3]=cmadd(acc[0][3],f0,v3);
            acc[1][0]=cmadd(acc[1][0],f1,v0); acc[1][1]=cmadd(acc[1][1],f1,v1);
            acc[1][2]=cmadd(acc[1][2],f1,v2); acc[1][3]=cmadd(acc[1][3],f1,v3);
            acc[2][0]=cmadd(acc[2][0],f2,v0); acc[2][1]=cmadd(acc[2][1],f2,v1);
            acc[2][2]=cmadd(acc[2][2],f2,v2); acc[2][3]=cmadd(acc[2][3],f2,v3);
            acc[3][0]=cmadd(acc[3][0],f3,v0); acc[3][1]=cmadd(acc[3][1],f3,v1);
            acc[3][2]=cmadd(acc[3][2],f3,v2); acc[3][3]=cmadd(acc[3][3],f3,v3);
        }

        // 4-stage jg reduction into T_s
        for (int st = 0; st < 4; ++st){
            if (jg == st){
                if (st == 0){
                    #pragma unroll
                    for (int u = 0; u < 4; ++u){
                        float4* Trow = (float4*)&T_s[lsq*4+u][0];  // 33 float4/row
                        Trow[colq*2]   = make_float4(acc[u][0].x, acc[u][0].y, acc[u][1].x, acc[u][1].y);
                        Trow[colq*2+1] = make_float4(acc[u][2].x, acc[u][2].y, acc[u][3].x, acc[u][3].y);
                    }
                } else {
                    #pragma unroll
                    for (int u = 0; u < 4; ++u){
                        #pragma unroll
                        for (int v = 0; v < 4; ++v){
                            float2 tp = T_s[lsq*4+u][colq*4+v];
                            tp.x += acc[u][v].x; tp.y += acc[u][v].y;
                            T_s[lsq*4+u][colq*4+v] = tp;
                        }
                    }
                }
            }
            __syncthreads();
        }
    }

    // ---- phase S: S[cl][qg] = sum_{lm} PK[lm][qg] * T[lm>>4][(lm&15)*4+cl]
    // wave = lsq2 owns lm in [lsq2*64, +64): PK read once per block total.
    {
        const int lsq2 = tid >> 6;         // wave index
        const int qg   = tid & 63;         // qr*4+g
        const float2* PKp = (const float2*)PK2 + qg;
        float2 sacc[4];
        #pragma unroll
        for (int cl = 0; cl < 4; ++cl) sacc[cl] = make_float2(0.f, 0.f);
        #pragma unroll 4
        for (int lml = 0; lml < 64; ++lml){
            const int lm = lsq2*64 + lml;
            float2 pk = PKp[(size_t)lm*64];
            const int ls = lm >> 4, mt4 = (lm & 15)*4;
            sacc[0] = cmadd(sacc[0], pk, T_s[ls][mt4]);
            sacc[1] = cmadd(sacc[1], pk, T_s[ls][mt4+1]);
            sacc[2] = cmadd(sacc[2], pk, T_s[ls][mt4+2]);
            sacc[3] = cmadd(sacc[3], pk, T_s[ls][mt4+3]);
        }
        // 4-stage lsq2 reduction into S_s[cl*64+qg]
        for (int st = 0; st < 4; ++st){
            if (lsq2 == st){
                if (st == 0){
                    #pragma unroll
                    for (int cl = 0; cl < 4; ++cl) S_s[cl*64 + qg] = sacc[cl];
                } else {
                    #pragma unroll
                    for (int cl = 0; cl < 4; ++cl){
                        float2 sp = S_s[cl*64 + qg];
                        sp.x += sacc[cl].x; sp.y += sacc[cl].y;
                        S_s[cl*64 + qg] = sp;
                    }
                }
            }
            __syncthreads();
        }
    }

    // ---- phase W (partial over this cq): Vout[qr][d] += sum_{cl,g} S*W
    {
        const int qr2 = tid >> 4, d = tid & 15;
        const int q = P2R_c[qr2];
        float2 acc = make_float2(0.f, 0.f);
        const float2* Wb = (const float2*)W_k + (size_t)q*16*4*16 + d;
        #pragma unroll
        for (int cl2 = 0; cl2 < 4; ++cl2){
            const int c = cq*4 + cl2;
            #pragma unroll
            for (int g2 = 0; g2 < 4; ++g2){
                float2 sv = S_s[cl2*64 + qr2*4 + g2];
                float2 wv = Wb[(c*4 + g2)*16];
                acc = cmadd(acc, sv, wv);
            }
        }
        float* outp = (float*)Vout + ((size_t)xi*256 + tid)*2;
        atomicAdd(outp,     acc.x);
        atomicAdd(outp + 1, acc.y);
    }
}

// unpack final packed V -> d_out (x,i,q,d,r,z), zeros at r >= DIMS[q]
__global__ void unpack_V_kernel(const float* __restrict__ Vp,
                                float* __restrict__ out){
    int idx = blockIdx.x*blockDim.x + threadIdx.x;
    if (idx >= XS*NP*4*16*7) return;
    int r  = idx % 7;
    int d  = (idx / 7) % 16;
    int q  = (idx / (7*16)) % 4;
    int xi = idx / (7*16*4);
    float2 v = make_float2(0.f, 0.f);
    if (r < DIMS_c[q]){
        v = ((const float2*)Vp)[(size_t)xi*256 + (OFF_c[q] + r)*16 + d];
    }
    ((float2*)out)[idx] = v;
}

extern "C" void kernel_launch(void* const* d_in, const int* in_sizes, int n_in,
                              void* d_out, int out_size, void* d_ws, size_t ws_size,
                              hipStream_t stream) {
    const float* X  = (const float*)d_in[0];
    // d_in[1] is 'l' (always 3, hardcoded)
    const float* V  = (const float*)d_in[2];
    const float* cg = (const float*)d_in[3];
    const float* f  = (const float*)d_in[4];
    const float* W  = (const float*)d_in[5];
    // d_in[6] is C4 (plain complex product, hardcoded)

    // ws layout (floats)
    float* ws     = (float*)d_ws;
    float* cgf    = ws;                         // 3*784*2   = 4704
    float* PK2    = cgf   + 4704;               // 16384*2   = 32768
    float* VA     = PK2   + 32768;              // 192*256*2 = 98304
    float* VB     = VA + 98304;                 // 98304
    float* VC     = VB + 98304;                 // 98304
    float* VD     = VC + 98304;                 // 98304
    float* filt_g = VD + 98304;                 // 3*192*96*16*2 = 1769472

    prep_kernel<<<(PREP_TOTAL + 255)/256, 256, 0, stream>>>(cg, f, V, cgf, PK2, VA);
    // filters for all layers + zero VB/VC/VD (contiguous)
    filt_all_kernel<<<NLAY*NXI + ZBLK, 256, 0, stream>>>(X, cgf, filt_g, VB);

    const float* W0 = W;
    const float* W1 = W + (size_t)1*4*16*4*16*2;
    const float* W2 = W + (size_t)2*4*16*4*16*2;
    const float* f0 = filt_g;
    const float* f1 = filt_g + (size_t)1*NXI*NP*16*2;
    const float* f2 = filt_g + (size_t)2*NXI*NP*16*2;

    TS_kernel<<<NXI*4, 256, 0, stream>>>(f0, PK2, W0, VA, VB);
    TS_kernel<<<NXI*4, 256, 0, stream>>>(f1, PK2, W1, VB, VC);
    TS_kernel<<<NXI*4, 256, 0, stream>>>(f2, PK2, W2, VC, VD);

    unpack_V_kernel<<<(XS*NP*4*16*7 + 255)/256, 256, 0, stream>>>(VD, (float*)d_out);
}